// Round 1
// 389.674 us; speedup vs baseline: 1.0024x; 1.0024x over previous
//
#include <hip/hip_runtime.h>

// GNN, fixed shapes: B=128 graphs x N=64 nodes, D=64 features, M=8192, HL=3, OL=2.
// adjacency [8192x8192] f32 is block-diagonal (128 diagonal 64x64 blocks), entries
// exactly 0.0/1.0, each block SYMMETRIC. All float tensors f32; fingerprints int32.
//
// ONE persistent kernel (128 blocks, co-resident on 256 CUs) does EVERYTHING:
// embed-gather + 3 message-passing layers + pooling + the 2-layer output MLP head
// + final projection. BatchNorm stats (batch-global) are exchanged via global
// atomics + a device-scope grid barrier (5 barriers total: 3 MP + 2 head).
// Key point for the head: after pooling, block b holds graph b's mol row in LDS,
// so the output MLP is row-local except the BN stats — no mol round-trip through
// global memory, no second kernel, no single-CU LDS-bound head GEMM.
#define MT   8192
#define DD   64
#define NPG  64
#define NB   128
#define XP   68          // padded column stride (floats) for xsc/wT
#define BN_EPS 1e-5f

__device__ __forceinline__ float selu_f(float x) {
  const float scale = 1.0507009873554804934f;
  const float alpha = 1.6732632423543772848f;
  return x > 0.f ? scale * x : scale * alpha * (__expf(x) - 1.f);
}

// Device-scope grid barrier (generation counter). All 128 blocks co-resident
// (128 blocks x 256 thr x ~63KB LDS on 256 CUs), so spinning is safe.
__device__ __forceinline__ void gbar(int* cnt, int* gen) {
  __syncthreads();
  if (threadIdx.x == 0) {
    int g = __hip_atomic_load(gen, __ATOMIC_RELAXED, __HIP_MEMORY_SCOPE_AGENT);
    int a = __hip_atomic_fetch_add(cnt, 1, __ATOMIC_ACQ_REL, __HIP_MEMORY_SCOPE_AGENT);
    if (a == (int)gridDim.x - 1) {
      __hip_atomic_store(cnt, 0, __ATOMIC_RELAXED, __HIP_MEMORY_SCOPE_AGENT);
      __hip_atomic_store(gen, g + 1, __ATOMIC_RELEASE, __HIP_MEMORY_SCOPE_AGENT);
    } else {
      while (__hip_atomic_load(gen, __ATOMIC_ACQUIRE, __HIP_MEMORY_SCOPE_AGENT) == g)
        __builtin_amdgcn_s_sleep(1);
    }
  }
  __syncthreads();
}

__global__ __launch_bounds__(256) void gnn_k(
    const int* __restrict__ fpr,
    const float* __restrict__ emb,     // [NFP,64]
    const float* __restrict__ adj,     // [8192,8192] block-diagonal 0/1
    const float* __restrict__ Wf,      // [3,64,64]
    const float* __restrict__ bfv,     // [3,64]
    const float* __restrict__ Wo,      // [2,64,64]
    const float* __restrict__ bo,      // [2,64]
    const float* __restrict__ Wp,      // [64]
    const float* __restrict__ bp,      // [1]
    float* __restrict__ out,           // [128] final output
    float* __restrict__ stats,         // [5*128] zeroed (sum|sumsq per BN)
    int* __restrict__ bar)             // [2] zeroed (cnt, gen)
{
  __shared__ float xsc[XP * 64];          // x column-major: xsc[d*XP + n]
  __shared__ float wT[XP * 64];           // wT[k*XP + c] = W[c][k]
  __shared__ float hs[64 * 64];           // h row-major: hs[n*64 + d]
  __shared__ unsigned char aU[64 * 64];   // A block bytes, aU[r*64 + k]
  __shared__ float mus[64], rss[64];
  __shared__ float red1[16 * 64], red2[16 * 64];  // dedicated (no wT overlay)
  __shared__ float mvec[64];              // pooled mol row of this graph

  const int tid = threadIdx.x, b = blockIdx.x;
  const int tr = tid >> 4, tc = tid & 15;
  const int n0 = tr * 4, c0 = tc * 4;

  // ---- stage A block (bytes), W^T(layer0), x (embed gather, col-major) ----
  for (int j = 0; j < 4; ++j) {
    int e = (tid + j * 256) * 4;
    int r = e >> 6, k = e & 63;
    float4 av = *(const float4*)(adj + (size_t)(b * NPG + r) * MT + b * NPG + k);
    uchar4 u;
    u.x = (unsigned char)av.x; u.y = (unsigned char)av.y;
    u.z = (unsigned char)av.z; u.w = (unsigned char)av.w;
    *(uchar4*)(aU + e) = u;
    float4 wv = *(const float4*)(Wf + e);          // W[r][k..k+3]
    wT[(k + 0) * XP + r] = wv.x;
    wT[(k + 1) * XP + r] = wv.y;
    wT[(k + 2) * XP + r] = wv.z;
    wT[(k + 3) * XP + r] = wv.w;
    int f = fpr[b * NPG + r];
    float4 xv = *(const float4*)(emb + (size_t)f * DD + k);
    xsc[(k + 0) * XP + r] = xv.x;
    xsc[(k + 1) * XP + r] = xv.y;
    xsc[(k + 2) * XP + r] = xv.z;
    xsc[(k + 3) * XP + r] = xv.w;
  }
  __syncthreads();

  float poolp = 0.f;   // this thread's pooling partial (layer 2)

  for (int l = 0; l < 3; ++l) {
    // ---- GEMM1: h = selu(x @ W^T + b) ----
    {
      float acc[4][4] = {};
#pragma unroll 4
      for (int d = 0; d < DD; ++d) {
        float4 xv = *(const float4*)(xsc + d * XP + n0);
        float4 wv = *(const float4*)(wT + d * XP + c0);
#pragma unroll
        for (int i = 0; i < 4; ++i) {
          float xk = ((const float*)&xv)[i];
          acc[i][0] += xk * wv.x;
          acc[i][1] += xk * wv.y;
          acc[i][2] += xk * wv.z;
          acc[i][3] += xk * wv.w;
        }
      }
      float b4[4];
#pragma unroll
      for (int c = 0; c < 4; ++c) b4[c] = bfv[l * DD + c0 + c];
#pragma unroll
      for (int i = 0; i < 4; ++i) {
        float4 hv;
        hv.x = selu_f(acc[i][0] + b4[0]);
        hv.y = selu_f(acc[i][1] + b4[1]);
        hv.z = selu_f(acc[i][2] + b4[2]);
        hv.w = selu_f(acc[i][3] + b4[3]);
        *(float4*)(hs + (n0 + i) * DD + c0) = hv;
      }
    }
    __syncthreads();   // hs ready; wT now dead until next layer's GEMM1

    // Prefetch next layer's W into registers — global-load latency overlaps
    // GEMM2 compute and the barrier wait (wT restage off the BN critical path).
    float4 wreg[4];
    if (l < 2) {
#pragma unroll
      for (int j = 0; j < 4; ++j)
        wreg[j] = *(const float4*)(Wf + (size_t)(l + 1) * 4096 + (size_t)(tid + j * 256) * 4);
    }

    // ---- GEMM2: y = x + A @ h (A read via symmetry: aU[k*64+n] = A[n][k]) ----
    {
      float acc[4][4] = {};
#pragma unroll 4
      for (int k = 0; k < DD; ++k) {
        uchar4 a4 = *(const uchar4*)(aU + k * DD + n0);
        float4 hv = *(const float4*)(hs + k * DD + c0);
        float af[4] = { (float)a4.x, (float)a4.y, (float)a4.z, (float)a4.w };
#pragma unroll
        for (int i = 0; i < 4; ++i) {
          acc[i][0] += af[i] * hv.x;
          acc[i][1] += af[i] * hv.y;
          acc[i][2] += af[i] * hv.z;
          acc[i][3] += af[i] * hv.w;
        }
      }
      // residual + in-place update of xsc (own cells only) + column stat partials
#pragma unroll
      for (int c = 0; c < 4; ++c) {
        float* p = xsc + (c0 + c) * XP + n0;
        float4 xo = *(const float4*)p;
        float y0 = acc[0][c] + xo.x;
        float y1 = acc[1][c] + xo.y;
        float y2 = acc[2][c] + xo.z;
        float y3 = acc[3][c] + xo.w;
        float4 yv = { y0, y1, y2, y3 };
        *(float4*)p = yv;
        red1[tr * DD + c0 + c] = y0 + y1 + y2 + y3;
        red2[tr * DD + c0 + c] = y0 * y0 + y1 * y1 + y2 * y2 + y3 * y3;
      }
    }
    __syncthreads();
    // 128 threads: t<64 reduce sums, t in [64,128) reduce sumsqs (layout matches stats)
    if (tid < 2 * DD) {
      const float* src = (tid < DD) ? red1 : (red2 - DD);
      int c = tid & 63;
      float t1 = 0.f;
#pragma unroll
      for (int q = 0; q < 16; ++q) t1 += src[q * DD + c + (tid & 64) * 0];
      // note: src already offset so src[q*DD + tid] indexes red1[q*DD+c] or red2[q*DD+c]
      atomicAdd(&stats[l * 128 + tid], t1);
      (void)c;
    }
    // restage wT for next layer from prefetched registers (wT dead since GEMM1)
    if (l < 2) {
#pragma unroll
      for (int j = 0; j < 4; ++j) {
        int e = (tid + j * 256) * 4;
        int r = e >> 6, k = e & 63;
        wT[(k + 0) * XP + r] = wreg[j].x;
        wT[(k + 1) * XP + r] = wreg[j].y;
        wT[(k + 2) * XP + r] = wreg[j].z;
        wT[(k + 3) * XP + r] = wreg[j].w;
      }
    }

    gbar(bar, bar + 1);   // batch-global BN stats complete

    if (tid < DD) {
      float s1 = __hip_atomic_load(&stats[l * 128 + tid], __ATOMIC_RELAXED,
                                   __HIP_MEMORY_SCOPE_AGENT);
      float s2 = __hip_atomic_load(&stats[l * 128 + DD + tid], __ATOMIC_RELAXED,
                                   __HIP_MEMORY_SCOPE_AGENT);
      float mu  = s1 * (1.f / MT);
      float var = fmaxf(s2 * (1.f / MT) - mu * mu, 0.f);
      mus[tid] = mu;
      rss[tid] = rsqrtf(var + BN_EPS);
    }
    __syncthreads();

    // ---- normalize xsc in place; thread owns column d = tid>>2, quarter q ----
    {
      int d = tid >> 2, q = tid & 3;
      float mu = mus[d], rs = rss[d];
      float* p = xsc + d * XP + q * 16;
      float ps = 0.f;
#pragma unroll
      for (int w = 0; w < 4; ++w) {
        float4 v = *(const float4*)(p + w * 4);
        v.x = (v.x - mu) * rs; v.y = (v.y - mu) * rs;
        v.z = (v.z - mu) * rs; v.w = (v.w - mu) * rs;
        *(float4*)(p + w * 4) = v;
        ps += v.x + v.y + v.z + v.w;
      }
      poolp = ps;
    }
    if (l == 2) red1[tid] = poolp;   // pooling partials
    __syncthreads();
  }

  // ---- pool: mean over the 64 nodes of this graph -> mvec (this graph's mol row)
  if (tid < DD)
    mvec[tid] = (red1[tid * 4] + red1[tid * 4 + 1] + red1[tid * 4 + 2] + red1[tid * 4 + 3])
                * (1.f / NPG);

  // ---- fused output MLP head: mol row is block-local; BN stats are global ----
  // wTo overlays xsc (dead): stride 65 -> 4160 floats <= 4352 available.
  float* wTo = xsc;
  float hn = 0.f;
  for (int j = 0; j < 2; ++j) {
    // stage Wo[j]^T: wTo[k*65 + c] = Wo[j][c][k]  (coalesced reads, 2-way LDS ok)
    for (int q = 0; q < 16; ++q) {
      int e = tid + q * 256;
      wTo[(e & 63) * 65 + (e >> 6)] = Wo[j * 4096 + e];
    }
    __syncthreads();
    float h = 0.f;
    if (tid < DD) {
      float acc = bo[j * DD + tid];
#pragma unroll 8
      for (int k = 0; k < DD; ++k)
        acc += mvec[k] * wTo[k * 65 + tid];   // mvec[k] broadcast; wTo 2-way
      h = selu_f(acc);
      atomicAdd(&stats[(3 + j) * 128 + tid], h);
      atomicAdd(&stats[(3 + j) * 128 + DD + tid], h * h);
    }
    gbar(bar, bar + 1);   // head BN stats complete (over 128 graph rows)
    if (tid < DD) {
      float s1 = __hip_atomic_load(&stats[(3 + j) * 128 + tid], __ATOMIC_RELAXED,
                                   __HIP_MEMORY_SCOPE_AGENT);
      float s2 = __hip_atomic_load(&stats[(3 + j) * 128 + DD + tid], __ATOMIC_RELAXED,
                                   __HIP_MEMORY_SCOPE_AGENT);
      float mu  = s1 * (1.f / NB);
      float var = fmaxf(s2 * (1.f / NB) - mu * mu, 0.f);
      hn = (h - mu) * rsqrtf(var + BN_EPS);
      if (j == 0) mvec[tid] = hn;   // feed next head layer
    }
    // next iteration's staging + __syncthreads orders mvec writes vs reads
  }

  // ---- final projection: out[b] = dot(hn_row, Wp) + bp (wave 0 only) ----
  if (tid < DD) {
    float p = hn * Wp[tid];
#pragma unroll
    for (int o = 32; o; o >>= 1) p += __shfl_down(p, o, 64);
    if (tid == 0) out[b] = p + bp[0];
  }
}

extern "C" void kernel_launch(void* const* d_in, const int* in_sizes, int n_in,
                              void* d_out, int out_size, void* d_ws, size_t ws_size,
                              hipStream_t stream) {
  (void)in_sizes; (void)n_in; (void)out_size; (void)ws_size;
  const int*   fpr = (const int*)d_in[0];
  const float* adj = (const float*)d_in[1];
  const float* emb = (const float*)d_in[2];
  const float* Wf  = (const float*)d_in[3];
  const float* bfv = (const float*)d_in[4];
  const float* Wo  = (const float*)d_in[5];
  const float* bo  = (const float*)d_in[6];
  const float* Wp  = (const float*)d_in[7];
  const float* bp  = (const float*)d_in[8];

  float* ws    = (float*)d_ws;
  float* stats = ws;                 // 5*128 floats (3 MP + 2 head BN stats)
  int*   bar   = (int*)(ws + 640);   // 2 ints (cnt, gen)

  hipMemsetAsync(ws, 0, (640 + 2) * sizeof(float), stream);

  gnn_k<<<NB, 256, 0, stream>>>(fpr, emb, adj, Wf, bfv, Wo, bo, Wp, bp,
                                (float*)d_out, stats, bar);
}